// Round 1
// baseline (1450.970 us; speedup 1.0000x reference)
//
#include <hip/hip_runtime.h>

#define NV 50000
#define NE 5000
#define NC 16
#define TAU_INV 2.0f
#define EPS 1e-8f
#define VCHUNK 1000
#define NCHUNK 50   // NV / VCHUNK

// ---------------- softmax: one thread per row, handles both pred_s and pred_t
__global__ __launch_bounds__(256) void softmax_kernel(
    const float* __restrict__ pred_s, const float* __restrict__ pred_t,
    float* __restrict__ ps, float* __restrict__ pt) {
  int i = blockIdx.x * 256 + threadIdx.x;
  if (i >= 2 * NV) return;
  const float* src;
  float* dst;
  if (i < NV) { src = pred_s + (size_t)i * NC; dst = ps + (size_t)i * NC; }
  else        { int j = i - NV; src = pred_t + (size_t)j * NC; dst = pt + (size_t)j * NC; }
  float4 a = ((const float4*)src)[0];
  float4 b = ((const float4*)src)[1];
  float4 c = ((const float4*)src)[2];
  float4 d = ((const float4*)src)[3];
  float x[16] = {a.x,a.y,a.z,a.w, b.x,b.y,b.z,b.w, c.x,c.y,c.z,c.w, d.x,d.y,d.z,d.w};
  float mx = x[0];
#pragma unroll
  for (int k = 1; k < 16; ++k) mx = fmaxf(mx, x[k]);
  float sum = 0.f;
#pragma unroll
  for (int k = 0; k < 16; ++k) { x[k] = expf(x[k] - mx); sum += x[k]; }
  float inv = 1.f / sum;
#pragma unroll
  for (int k = 0; k < 16; ++k) x[k] *= inv;
  float4 o0 = {x[0], x[1], x[2], x[3]};
  float4 o1 = {x[4], x[5], x[6], x[7]};
  float4 o2 = {x[8], x[9], x[10], x[11]};
  float4 o3 = {x[12], x[13], x[14], x[15]};
  ((float4*)dst)[0] = o0;
  ((float4*)dst)[1] = o1;
  ((float4*)dst)[2] = o2;
  ((float4*)dst)[3] = o3;
}

// ---------------- main accumulation: lane<->edge, loop over a V-chunk.
// acc layout (floats): deg[NE] | S[16][NE] | T[16][NE]
__global__ __launch_bounds__(256) void accum_kernel(
    const float* __restrict__ H, const float* __restrict__ ps,
    const float* __restrict__ pt, float* __restrict__ acc) {
  int e = blockIdx.x * 256 + threadIdx.x;
  if (e >= NE) return;
  int v0 = blockIdx.y * VCHUNK;

  float deg = 0.f;
  float as[16], at[16];
#pragma unroll
  for (int k = 0; k < 16; ++k) { as[k] = 0.f; at[k] = 0.f; }

  const float* hp = H + (size_t)v0 * NE + e;
  for (int v = v0; v < v0 + VCHUNK; v += 4) {
    float h0 = hp[0];
    float h1 = hp[NE];
    float h2 = hp[2 * NE];
    float h3 = hp[3 * NE];
    hp += (size_t)4 * NE;
#pragma unroll
    for (int u = 0; u < 4; ++u) {
      float h = (u == 0) ? h0 : (u == 1) ? h1 : (u == 2) ? h2 : h3;
      const float* rs = ps + (size_t)(v + u) * NC;
      const float* rt = pt + (size_t)(v + u) * NC;
      float4 sA = ((const float4*)rs)[0];
      float4 sB = ((const float4*)rs)[1];
      float4 sC = ((const float4*)rs)[2];
      float4 sD = ((const float4*)rs)[3];
      float4 tA = ((const float4*)rt)[0];
      float4 tB = ((const float4*)rt)[1];
      float4 tC = ((const float4*)rt)[2];
      float4 tD = ((const float4*)rt)[3];
      float sv[16] = {sA.x,sA.y,sA.z,sA.w, sB.x,sB.y,sB.z,sB.w,
                      sC.x,sC.y,sC.z,sC.w, sD.x,sD.y,sD.z,sD.w};
      float tv[16] = {tA.x,tA.y,tA.z,tA.w, tB.x,tB.y,tB.z,tB.w,
                      tC.x,tC.y,tC.z,tC.w, tD.x,tD.y,tD.z,tD.w};
      deg += h;
#pragma unroll
      for (int k = 0; k < 16; ++k) as[k] = fmaf(h, sv[k], as[k]);
#pragma unroll
      for (int k = 0; k < 16; ++k) at[k] = fmaf(h, tv[k], at[k]);
    }
  }

  atomicAdd(&acc[e], deg);
#pragma unroll
  for (int k = 0; k < 16; ++k)
    atomicAdd(&acc[NE + (size_t)k * NE + e], as[k]);
#pragma unroll
  for (int k = 0; k < 16; ++k)
    atomicAdd(&acc[(size_t)17 * NE + (size_t)k * NE + e], at[k]);
}

// ---------------- per-edge KL + masked reduction (single block)
__global__ __launch_bounds__(256) void kl_kernel(
    const float* __restrict__ acc, const unsigned char* __restrict__ e_mask,
    float* __restrict__ out) {
  __shared__ float snum[256];
  __shared__ float scnt[256];
  int t = threadIdx.x;
  float num = 0.f, cnt = 0.f;
  for (int e = t; e < NE; e += 256) {
    if (e_mask[e]) {
      float deg = acc[e];
      float invd = 1.f / deg;
      float kl = 0.f;
#pragma unroll
      for (int k = 0; k < 16; ++k) {
        float ms = acc[NE + (size_t)k * NE + e] * invd;
        float mt = acc[(size_t)17 * NE + (size_t)k * NE + e] * invd;
        float xs = ms * TAU_INV + EPS;
        float xt = mt * TAU_INV + EPS;
        kl += xt * (logf(xt) - logf(xs));
      }
      num += kl;
      cnt += 1.f;
    }
  }
  snum[t] = num;
  scnt[t] = cnt;
  __syncthreads();
  if (t == 0) {
    float n = 0.f, c2 = 0.f;
    for (int k = 0; k < 256; ++k) { n += snum[k]; c2 += scnt[k]; }
    out[0] = n / fmaxf(c2, 1.f);
  }
}

extern "C" void kernel_launch(void* const* d_in, const int* in_sizes, int n_in,
                              void* d_out, int out_size, void* d_ws, size_t ws_size,
                              hipStream_t stream) {
  const float* pred_s = (const float*)d_in[0];
  const float* pred_t = (const float*)d_in[1];
  const float* H      = (const float*)d_in[2];
  const unsigned char* e_mask = (const unsigned char*)d_in[3];

  float* ws = (float*)d_ws;
  float* ps  = ws;                          // NV*NC floats
  float* pt  = ws + (size_t)NV * NC;        // NV*NC floats
  float* acc = ws + (size_t)2 * NV * NC;    // 33*NE floats

  hipMemsetAsync(acc, 0, (size_t)33 * NE * sizeof(float), stream);
  softmax_kernel<<<dim3((2 * NV + 255) / 256), 256, 0, stream>>>(pred_s, pred_t, ps, pt);
  accum_kernel<<<dim3((NE + 255) / 256, NCHUNK), 256, 0, stream>>>(H, ps, pt, acc);
  kl_kernel<<<1, 256, 0, stream>>>(acc, e_mask, (float*)d_out);
}

// Round 2
// 1447.840 us; speedup vs baseline: 1.0022x; 1.0022x over previous
//
#include <hip/hip_runtime.h>

#define NV 50000
#define NE 5000
#define NC 16
#define TAU_INV 2.0f
#define EPS 1e-8f
#define VCHUNK 1000
#define NCHUNK 50   // NV / VCHUNK

// ---------------- softmax: one thread per row, handles both pred_s and pred_t.
// Output layout: p[v][32] = [softmax(pred_s[v]) (16) | softmax(pred_t[v]) (16)]
__global__ __launch_bounds__(256) void softmax_kernel(
    const float* __restrict__ pred_s, const float* __restrict__ pred_t,
    float* __restrict__ p) {
  int i = blockIdx.x * 256 + threadIdx.x;
  if (i >= 2 * NV) return;
  const float* src;
  float* dst;
  if (i < NV) { src = pred_s + (size_t)i * NC; dst = p + (size_t)i * 32; }
  else        { int j = i - NV; src = pred_t + (size_t)j * NC; dst = p + (size_t)j * 32 + 16; }
  float4 a = ((const float4*)src)[0];
  float4 b = ((const float4*)src)[1];
  float4 c = ((const float4*)src)[2];
  float4 d = ((const float4*)src)[3];
  float x[16] = {a.x,a.y,a.z,a.w, b.x,b.y,b.z,b.w, c.x,c.y,c.z,c.w, d.x,d.y,d.z,d.w};
  float mx = x[0];
#pragma unroll
  for (int k = 1; k < 16; ++k) mx = fmaxf(mx, x[k]);
  float sum = 0.f;
#pragma unroll
  for (int k = 0; k < 16; ++k) { x[k] = expf(x[k] - mx); sum += x[k]; }
  float inv = 1.f / sum;
#pragma unroll
  for (int k = 0; k < 16; ++k) x[k] *= inv;
  float4 o0 = {x[0], x[1], x[2], x[3]};
  float4 o1 = {x[4], x[5], x[6], x[7]};
  float4 o2 = {x[8], x[9], x[10], x[11]};
  float4 o3 = {x[12], x[13], x[14], x[15]};
  ((float4*)dst)[0] = o0;
  ((float4*)dst)[1] = o1;
  ((float4*)dst)[2] = o2;
  ((float4*)dst)[3] = o3;
}

// ---------------- main accumulation: lane<->edge (coalesced H stream),
// p rows are wave-uniform -> should lower to s_load (SMEM pipe).
// acc layout (floats): deg[NE] | S[16][NE] | T[16][NE]
__global__ __launch_bounds__(256, 4) void accum_kernel(
    const float* __restrict__ H, const float* __restrict__ p,
    float* __restrict__ acc) {
  int te = blockIdx.x * 256 + threadIdx.x;
  // No divergence in the main loop: clamp the edge index, predicate the
  // atomics at the end. (Early return here blocks uniform->s_load lowering.)
  int e = te < NE ? te : NE - 1;
  int v0 = blockIdx.y * VCHUNK;

  float deg = 0.f;
  float as[16], at[16];
#pragma unroll
  for (int k = 0; k < 16; ++k) { as[k] = 0.f; at[k] = 0.f; }

  const float* __restrict__ hp = H + (size_t)v0 * NE + e;
  const float* __restrict__ pp = p + (size_t)v0 * 32;

#pragma unroll 2
  for (int v = 0; v < VCHUNK; ++v) {
    float h = hp[(size_t)v * NE];
    // Wave-uniform address, read-only, non-divergent -> scalar loads.
    float4 sA = ((const float4*)(pp + (size_t)v * 32))[0];
    float4 sB = ((const float4*)(pp + (size_t)v * 32))[1];
    float4 sC = ((const float4*)(pp + (size_t)v * 32))[2];
    float4 sD = ((const float4*)(pp + (size_t)v * 32))[3];
    float4 tA = ((const float4*)(pp + (size_t)v * 32))[4];
    float4 tB = ((const float4*)(pp + (size_t)v * 32))[5];
    float4 tC = ((const float4*)(pp + (size_t)v * 32))[6];
    float4 tD = ((const float4*)(pp + (size_t)v * 32))[7];
    float sv[16] = {sA.x,sA.y,sA.z,sA.w, sB.x,sB.y,sB.z,sB.w,
                    sC.x,sC.y,sC.z,sC.w, sD.x,sD.y,sD.z,sD.w};
    float tv[16] = {tA.x,tA.y,tA.z,tA.w, tB.x,tB.y,tB.z,tB.w,
                    tC.x,tC.y,tC.z,tC.w, tD.x,tD.y,tD.z,tD.w};
    deg += h;
#pragma unroll
    for (int k = 0; k < 16; ++k) as[k] = fmaf(h, sv[k], as[k]);
#pragma unroll
    for (int k = 0; k < 16; ++k) at[k] = fmaf(h, tv[k], at[k]);
  }

  if (te < NE) {
    atomicAdd(&acc[e], deg);
#pragma unroll
    for (int k = 0; k < 16; ++k)
      atomicAdd(&acc[NE + (size_t)k * NE + e], as[k]);
#pragma unroll
    for (int k = 0; k < 16; ++k)
      atomicAdd(&acc[(size_t)17 * NE + (size_t)k * NE + e], at[k]);
  }
}

// ---------------- per-edge KL + masked reduction (single block, 256 threads)
__global__ __launch_bounds__(256) void kl_kernel(
    const float* __restrict__ acc, const unsigned char* __restrict__ e_mask,
    float* __restrict__ out) {
  __shared__ float snum[4];
  __shared__ float scnt[4];
  int t = threadIdx.x;
  float num = 0.f, cnt = 0.f;
  for (int e = t; e < NE; e += 256) {
    if (e_mask[e]) {
      float deg = acc[e];
      float invd = 1.f / deg;
      float kl = 0.f;
#pragma unroll
      for (int k = 0; k < 16; ++k) {
        float ms = acc[NE + (size_t)k * NE + e] * invd;
        float mt = acc[(size_t)17 * NE + (size_t)k * NE + e] * invd;
        float xs = ms * TAU_INV + EPS;
        float xt = mt * TAU_INV + EPS;
        kl += xt * (logf(xt) - logf(xs));
      }
      num += kl;
      cnt += 1.f;
    }
  }
  // wave reduce (64 lanes), then 4 partials via LDS
#pragma unroll
  for (int off = 32; off > 0; off >>= 1) {
    num += __shfl_down(num, off, 64);
    cnt += __shfl_down(cnt, off, 64);
  }
  if ((t & 63) == 0) { snum[t >> 6] = num; scnt[t >> 6] = cnt; }
  __syncthreads();
  if (t == 0) {
    float n = snum[0] + snum[1] + snum[2] + snum[3];
    float c2 = scnt[0] + scnt[1] + scnt[2] + scnt[3];
    out[0] = n / fmaxf(c2, 1.f);
  }
}

extern "C" void kernel_launch(void* const* d_in, const int* in_sizes, int n_in,
                              void* d_out, int out_size, void* d_ws, size_t ws_size,
                              hipStream_t stream) {
  const float* pred_s = (const float*)d_in[0];
  const float* pred_t = (const float*)d_in[1];
  const float* H      = (const float*)d_in[2];
  const unsigned char* e_mask = (const unsigned char*)d_in[3];

  float* ws = (float*)d_ws;
  float* p   = ws;                          // NV*32 floats (s|t interleaved rows)
  float* acc = ws + (size_t)NV * 32;        // 33*NE floats

  hipMemsetAsync(acc, 0, (size_t)33 * NE * sizeof(float), stream);
  softmax_kernel<<<dim3((2 * NV + 255) / 256), 256, 0, stream>>>(pred_s, pred_t, p);
  accum_kernel<<<dim3((NE + 255) / 256, NCHUNK), 256, 0, stream>>>(H, p, acc);
  kl_kernel<<<1, 256, 0, stream>>>(acc, e_mask, (float*)d_out);
}